// Round 1
// baseline (12.341 us; speedup 1.0000x reference)
//
#include <hip/hip_runtime.h>
#include <hip/hip_bf16.h>
#include <math.h>

// Problem geometry (fixed by setup_inputs): feature [1,2,96,160] f32,
// boxes [128,4] f32, fc_w [4, 2*7*7] f32, fc_b [4] f32. Output [128,4] f32.
// out = relu(adaptive_maxpool7x7(crop) @ fc_w.T + fc_b) + boxes
//
// Adaptive-pool cell i over a crop [lo, hi) of length h covers rows
// [lo + floor(i*h/7), lo + ceil((i+1)*h/7)).  Box coords are int32-truncated.

#define C_ 2
#define H_ 96
#define W_ 160
#define P_ 7
#define CELLS (C_ * P_ * P_)  // 98

__global__ void roi_pool_fc_kernel(const float* __restrict__ feature, // [C,H,W]
                                   const float* __restrict__ boxes,   // [N,4]
                                   const float* __restrict__ fc_w,    // [4,98]
                                   const float* __restrict__ fc_b,    // [4]
                                   float* __restrict__ out)           // [N,4]
{
    const int n = blockIdx.x;
    const int t = threadIdx.x;

    __shared__ float pooled[CELLS];
    __shared__ float sbox[4];

    if (t < 4) sbox[t] = boxes[n * 4 + t];
    __syncthreads();

    // int() truncation (boxes are positive -> floor)
    const int x1 = (int)sbox[0];
    const int y1 = (int)sbox[1];
    const int x2 = (int)sbox[2];
    const int y2 = (int)sbox[3];
    const int hh = y2 - y1;   // >= 5 by construction
    const int ww = x2 - x1;

    if (t < CELLS) {
        const int c   = t / (P_ * P_);
        const int rem = t % (P_ * P_);
        const int py  = rem / P_;
        const int px  = rem % P_;

        const int rs = y1 + (py * hh) / P_;
        const int re = y1 + ((py + 1) * hh + (P_ - 1)) / P_;  // ceil
        const int cs = x1 + (px * ww) / P_;
        const int ce = x1 + ((px + 1) * ww + (P_ - 1)) / P_;

        float m = -INFINITY;
        const float* __restrict__ f = feature + c * (H_ * W_);
        for (int r = rs; r < re; ++r) {
            const float* __restrict__ row = f + r * W_;
            for (int cc = cs; cc < ce; ++cc)
                m = fmaxf(m, row[cc]);
        }
        pooled[t] = m;
    }
    __syncthreads();

    if (t < 4) {
        float acc = fc_b[t];
        const float* __restrict__ w = fc_w + t * CELLS;
        #pragma unroll 14
        for (int k = 0; k < CELLS; ++k)
            acc = fmaf(pooled[k], w[k], acc);
        out[n * 4 + t] = fmaxf(acc, 0.f) + sbox[t];
    }
}

extern "C" void kernel_launch(void* const* d_in, const int* in_sizes, int n_in,
                              void* d_out, int out_size, void* d_ws, size_t ws_size,
                              hipStream_t stream) {
    const float* feature = (const float*)d_in[0];
    const float* boxes   = (const float*)d_in[1];
    const float* fc_w    = (const float*)d_in[2];
    const float* fc_b    = (const float*)d_in[3];
    float* out = (float*)d_out;

    const int N = in_sizes[1] / 4;  // 128

    roi_pool_fc_kernel<<<N, 128, 0, stream>>>(feature, boxes, fc_w, fc_b, out);
}

// Round 2
// 9.605 us; speedup vs baseline: 1.2849x; 1.2849x over previous
//
#include <hip/hip_runtime.h>
#include <hip/hip_bf16.h>
#include <math.h>

// feature [1,2,96,160] f32, boxes [128,4] f32, fc_w [4,98] f32, fc_b [4] f32.
// out[n] = relu(adaptive_maxpool7x7(crop_n) . fc_w^T + fc_b) + boxes[n]
//
// PyTorch adaptive cell i over [lo,hi), h=hi-lo: rows [lo+floor(i*h/7),
// lo+ceil((i+1)*h/7)). Box coords int-truncated. h,w in [5,48] =>
// every cell spans <= 8 rows x 8 cols, and the 8x8 window anchored at
// (rs,cs) is always inside the 96x160 map (x1<=W-49, y1<=H-49).
//
// Key change vs R1: fixed-trip fully-unrolled 8x8 window load (64 global
// loads issued in one batch -> ONE vmcnt wait instead of 64 serial
// load->wait->max round-trips), then predicated max reduce.

#define C_ 2
#define H_ 96
#define W_ 160
#define P_ 7
#define CELLS (C_ * P_ * P_)  // 98

__global__ void __launch_bounds__(128)
roi_pool_fc_kernel(const float* __restrict__ feature, // [C,H,W]
                   const float* __restrict__ boxes,   // [N,4]
                   const float* __restrict__ fc_w,    // [4,98]
                   const float* __restrict__ fc_b,    // [4]
                   float* __restrict__ out)           // [N,4]
{
    const int n = blockIdx.x;
    const int t = threadIdx.x;

    __shared__ float pooled[CELLS];

    // Uniform (block-constant) address -> compiler emits scalar loads.
    const float bx1 = boxes[n * 4 + 0];
    const float by1 = boxes[n * 4 + 1];
    const float bx2 = boxes[n * 4 + 2];
    const float by2 = boxes[n * 4 + 3];

    const int x1 = (int)bx1;   // coords positive -> trunc == floor
    const int y1 = (int)by1;
    const int x2 = (int)bx2;
    const int y2 = (int)by2;
    const int hh = y2 - y1;    // in [5,48]
    const int ww = x2 - x1;

    if (t < CELLS) {
        const int c   = t / (P_ * P_);
        const int rem = t % (P_ * P_);
        const int py  = rem / P_;
        const int px  = rem % P_;

        const int rs = y1 + (py * hh) / P_;
        const int re = y1 + ((py + 1) * hh + (P_ - 1)) / P_;  // ceil
        const int cs = x1 + (px * ww) / P_;
        const int ce = x1 + ((px + 1) * ww + (P_ - 1)) / P_;
        const int nr = re - rs;  // 1..8
        const int nc = ce - cs;  // 1..8

        const float* __restrict__ base = feature + c * (H_ * W_) + rs * W_ + cs;

        // Batch all 64 window loads (registers, static indexing).
        float v[64];
        #pragma unroll
        for (int i = 0; i < 64; ++i)
            v[i] = base[(i >> 3) * W_ + (i & 7)];

        float m = -INFINITY;
        #pragma unroll
        for (int i = 0; i < 64; ++i) {
            const bool ok = ((i >> 3) < nr) & ((i & 7) < nc);
            m = fmaxf(m, ok ? v[i] : -INFINITY);
        }
        pooled[t] = m;
    }
    __syncthreads();

    if (t < 4) {
        float w[CELLS], p[CELLS];
        const float* __restrict__ wrow = fc_w + t * CELLS;
        #pragma unroll
        for (int k = 0; k < CELLS; ++k) w[k] = wrow[k];
        #pragma unroll
        for (int k = 0; k < CELLS; ++k) p[k] = pooled[k];
        float acc = fc_b[t];
        #pragma unroll
        for (int k = 0; k < CELLS; ++k)
            acc = fmaf(p[k], w[k], acc);
        const float bc = boxes[n * 4 + t];
        out[n * 4 + t] = fmaxf(acc, 0.f) + bc;
    }
}

extern "C" void kernel_launch(void* const* d_in, const int* in_sizes, int n_in,
                              void* d_out, int out_size, void* d_ws, size_t ws_size,
                              hipStream_t stream) {
    const float* feature = (const float*)d_in[0];
    const float* boxes   = (const float*)d_in[1];
    const float* fc_w    = (const float*)d_in[2];
    const float* fc_b    = (const float*)d_in[3];
    float* out = (float*)d_out;

    const int N = in_sizes[1] / 4;  // 128

    roi_pool_fc_kernel<<<N, 128, 0, stream>>>(feature, boxes, fc_w, fc_b, out);
}